// Round 1
// 3884.267 us; speedup vs baseline: 1.5125x; 1.5125x over previous
//
#include <hip/hip_runtime.h>
#include <hip/hip_fp16.h>
#include <math.h>

// Problem constants: SEQ=256, B=32, NVOC=10000, NIN=NH=256, gates=4
#define SEQ   256
#define BATCH 32
#define NVOC  10000
#define NH    256
#define NG4   1024          // NH*4 gate columns
#define MTOT  8192          // SEQ*BATCH

// Generic K=256 f32 GEMM: C[M=8192][N] = A[8192][256] * B[256][N] + bias[N]
// AMODE 0: A rows gathered from embed_W via tokens; AMODE 1: A dense f32.
// BT false: B row-major [256][N]; BT true: B[k][n] = Bsrc[n*256+k] (dec_W is [NVOC][NH])
template<int AMODE, bool BT>
__global__ __launch_bounds__(256)
void gemm_k256(const float* __restrict__ Aptr, const int* __restrict__ tokens,
               const float* __restrict__ Bptr, const float* __restrict__ bias,
               float* __restrict__ Cptr, int N)
{
    __shared__ __align__(16) float As[32][68];   // [k][m], +4 pad: float4-aligned rows, no conflicts
    __shared__ __align__(16) float Bs[32][68];   // [k][n]
    __shared__ int rowTok[64];

    const int tid  = threadIdx.x;
    const int row0 = blockIdx.x * 64;
    const int col0 = blockIdx.y * 64;

    if (AMODE == 0) {
        if (tid < 64) rowTok[tid] = tokens[row0 + tid];
        __syncthreads();
    }

    float acc[4][4] = {};
    const int ty = tid >> 4, tx = tid & 15;    // 16x16 thread grid, 4x4 outputs each
    const int lr = tid >> 2, lq = tid & 3;     // loader: row 0..63, 8-elem segment 0..3

    for (int kb = 0; kb < 256; kb += 32) {
        // ---- global -> regs ----
        float av[8];
        {
            const int arow = (AMODE == 0) ? rowTok[lr] : (row0 + lr);
            const float* src = Aptr + (size_t)arow * 256 + kb + lq * 8;
            float4 v0 = *(const float4*)src;
            float4 v1 = *(const float4*)(src + 4);
            av[0]=v0.x; av[1]=v0.y; av[2]=v0.z; av[3]=v0.w;
            av[4]=v1.x; av[5]=v1.y; av[6]=v1.z; av[7]=v1.w;
        }
        float bv[8];
        if (!BT) {
            const int kk = tid >> 3, sg = tid & 7;   // 32 k-rows x 8 segments
            const float* src = Bptr + (size_t)(kb + kk) * N + col0 + sg * 8;
            float4 v0 = *(const float4*)src;
            float4 v1 = *(const float4*)(src + 4);
            bv[0]=v0.x; bv[1]=v0.y; bv[2]=v0.z; bv[3]=v0.w;
            bv[4]=v1.x; bv[5]=v1.y; bv[6]=v1.z; bv[7]=v1.w;
        } else {
            const int gcol = col0 + lr;
            if (gcol < N) {
                const float* src = Bptr + (size_t)gcol * 256 + kb + lq * 8;
                float4 v0 = *(const float4*)src;
                float4 v1 = *(const float4*)(src + 4);
                bv[0]=v0.x; bv[1]=v0.y; bv[2]=v0.z; bv[3]=v0.w;
                bv[4]=v1.x; bv[5]=v1.y; bv[6]=v1.z; bv[7]=v1.w;
            } else {
                #pragma unroll
                for (int j = 0; j < 8; j++) bv[j] = 0.f;
            }
        }

        __syncthreads();   // previous tile's LDS reads complete before overwrite
        #pragma unroll
        for (int j = 0; j < 8; j++) As[lq * 8 + j][lr] = av[j];
        if (!BT) {
            const int kk = tid >> 3, sg = tid & 7;
            #pragma unroll
            for (int j = 0; j < 8; j++) Bs[kk][sg * 8 + j] = bv[j];
        } else {
            #pragma unroll
            for (int j = 0; j < 8; j++) Bs[lq * 8 + j][lr] = bv[j];
        }
        __syncthreads();

        // ---- inner product ----
        #pragma unroll
        for (int kk = 0; kk < 32; kk++) {
            float4 af = *(const float4*)(&As[kk][ty * 4]);
            float4 bf = *(const float4*)(&Bs[kk][tx * 4]);
            float ar[4] = {af.x, af.y, af.z, af.w};
            float br[4] = {bf.x, bf.y, bf.z, bf.w};
            #pragma unroll
            for (int i = 0; i < 4; i++)
                #pragma unroll
                for (int j = 0; j < 4; j++)
                    acc[i][j] = fmaf(ar[i], br[j], acc[i][j]);
        }
    }

    // ---- epilogue: bias + store ----
    #pragma unroll
    for (int i = 0; i < 4; i++) {
        const int row = row0 + ty * 4 + i;     // M=8192 divisible by 64 -> always valid
        #pragma unroll
        for (int j = 0; j < 4; j++) {
            const int col = col0 + tx * 4 + j;
            if (col < N)
                Cptr[(size_t)row * N + col] = acc[i][j] + bias[col];
        }
    }
}

// Repack recurrent weights: Wh f32 [256 h][1024 col] -> fp16 h-chunked layout
// Wt stored as float4 (8 halfs): chunk ch (8 h's), col:  Wt4[ch*1024 + col].h[j] = Wh[ch*8+j][col]
// Per-wave lstm read of (chunk, col=lane) is then a fully coalesced 1KB b128 stream.
__global__ __launch_bounds__(256)
void pack_wh(const float* __restrict__ Wh, float4* __restrict__ Wt4)
{
    const int idx   = blockIdx.x * 256 + threadIdx.x;  // 0..32767 = chunk*1024 + col
    const int chunk = idx >> 10;
    const int col   = idx & 1023;
    const float* src = Wh + (size_t)(chunk * 8) * NG4 + col;  // stride NG4 over j (coalesced per j)
    union { __half h[8]; float4 v; } u;
    #pragma unroll
    for (int j = 0; j < 8; ++j)
        u.h[j] = __float2half(src[(size_t)j * NG4]);
    Wt4[idx] = u.v;
}

// LSTM recurrence, one workgroup per batch element (grid=32, block=1024).
// gx: [SEQ*B][1024] f32 (bias already included). Wt: fp16 chunked (see pack_wh).
// hseq out: [SEQ*B][256] f32. h,c start at zero.
// Weight stream per step is now 512KB (fp16) via 32 coalesced b128 loads/thread:
// halves the per-CU L2->L1 fill bytes that bound the old kernel (~9.4us/step).
__global__ __launch_bounds__(1024)
void lstm_layer(const float* __restrict__ gx, const __half* __restrict__ Wt,
                float* __restrict__ hseq)
{
    const int b   = blockIdx.x;
    const int tid = threadIdx.x;          // gate column: k = tid>>2, g = tid&3
    __shared__ __align__(16) float hbuf[NH];
    __shared__ __align__(16) float zbuf[NG4];
    float c = 0.f;
    if (tid < NH) hbuf[tid] = 0.f;
    __syncthreads();

    const __half* __restrict__ wp = Wt + (size_t)tid * 8;  // this column's chunk-0 slot

    for (int t = 0; t < SEQ; ++t) {
        float a0 = gx[((size_t)t * BATCH + b) * NG4 + tid];
        float a1 = 0.f, a2 = 0.f, a3 = 0.f;
        #pragma unroll 4
        for (int ch = 0; ch < 32; ++ch) {
            float4 wraw = *reinterpret_cast<const float4*>(wp + (size_t)ch * (NG4 * 8));
            const __half2* wh2 = reinterpret_cast<const __half2*>(&wraw);
            const float4 hA = *reinterpret_cast<const float4*>(&hbuf[ch * 8]);     // broadcast
            const float4 hB = *reinterpret_cast<const float4*>(&hbuf[ch * 8 + 4]); // broadcast
            float2 w01 = __half22float2(wh2[0]);
            float2 w23 = __half22float2(wh2[1]);
            float2 w45 = __half22float2(wh2[2]);
            float2 w67 = __half22float2(wh2[3]);
            a0 = fmaf(w01.x, hA.x, a0);
            a1 = fmaf(w01.y, hA.y, a1);
            a2 = fmaf(w23.x, hA.z, a2);
            a3 = fmaf(w23.y, hA.w, a3);
            a0 = fmaf(w45.x, hB.x, a0);
            a1 = fmaf(w45.y, hB.y, a1);
            a2 = fmaf(w67.x, hB.z, a2);
            a3 = fmaf(w67.y, hB.w, a3);
        }
        zbuf[tid] = (a0 + a1) + (a2 + a3);
        __syncthreads();                         // all hbuf reads + zbuf writes done
        if (tid < NH) {
            const float4 z4 = *reinterpret_cast<const float4*>(&zbuf[tid * 4]);
            float ig = 1.f / (1.f + expf(-z4.x));
            float fg = 1.f / (1.f + expf(-z4.y));
            float og = 1.f / (1.f + expf(-z4.z));
            float gg = tanhf(z4.w);
            c = fmaf(fg, c, ig * gg);
            float hn = og * tanhf(c);
            hbuf[tid] = hn;                      // safe: all readers past barrier above
            hseq[((size_t)t * BATCH + b) * NH + tid] = hn;
        }
        __syncthreads();                         // hbuf updated before next step's reads
    }
}

// h1 = layer0 last hidden, h2 = layer1 last hidden -> appended to d_out (f32)
__global__ __launch_bounds__(256)
void copy_hlast(const float* __restrict__ h1seq, const float* __restrict__ h2seq,
                float* __restrict__ out)
{
    const int i = blockIdx.x * 256 + threadIdx.x;          // 0..8191 = b*256+k
    const size_t lastoff = (size_t)(SEQ - 1) * BATCH * NH; // 2088960
    out[(size_t)MTOT * NVOC + i]        = h1seq[lastoff + i];
    out[(size_t)MTOT * NVOC + 8192 + i] = h2seq[lastoff + i];
}

extern "C" void kernel_launch(void* const* d_in, const int* in_sizes, int n_in,
                              void* d_out, int out_size, void* d_ws, size_t ws_size,
                              hipStream_t stream)
{
    const int*   tokens = (const int*)d_in[0];
    const float* embed  = (const float*)d_in[1];
    const float* Wx0    = (const float*)d_in[2];
    const float* Wh0    = (const float*)d_in[3];
    const float* b0     = (const float*)d_in[4];
    const float* Wx1    = (const float*)d_in[5];
    const float* Wh1    = (const float*)d_in[6];
    const float* b1     = (const float*)d_in[7];
    const float* decW   = (const float*)d_in[8];
    const float* decb   = (const float*)d_in[9];

    float* out = (float*)d_out;

    // Scratch: gx[8192][1024] f32 (33.5 MB) lives in the FRONT of d_out (328 MB),
    // followed by the two fp16 repacked Wh's (0.5 MB each); the decoder GEMM fully
    // overwrites all of it at the end. d_ws holds h1seq/h2seq only.
    float*  gx    = out;
    __half* Wt0   = reinterpret_cast<__half*>(out + (size_t)MTOT * NG4); // byte off 33,554,432 (16B-aligned)
    __half* Wt1   = Wt0 + (size_t)NG4 * NH;                              // +262,144 halfs
    float*  h1seq = (float*)d_ws;                 // 8,388,608 B
    float*  h2seq = h1seq + (size_t)MTOT * NH;    // 8,388,608 B (total 16.8 MB of ws)

    // repack recurrent weights to fp16 chunked layout (independent of the gx GEMMs)
    pack_wh<<<128, 256, 0, stream>>>(Wh0, reinterpret_cast<float4*>(Wt0));
    pack_wh<<<128, 256, 0, stream>>>(Wh1, reinterpret_cast<float4*>(Wt1));

    // layer 0: gate inputs (embedding gather fused) then recurrence
    gemm_k256<0, false><<<dim3(128, 16), 256, 0, stream>>>(embed, tokens, Wx0, b0, gx, NG4);
    lstm_layer<<<32, 1024, 0, stream>>>(gx, Wt0, h1seq);

    // layer 1
    gemm_k256<1, false><<<dim3(128, 16), 256, 0, stream>>>(h1seq, nullptr, Wx1, b1, gx, NG4);
    lstm_layer<<<32, 1024, 0, stream>>>(gx, Wt1, h2seq);

    // decoder: [8192,256] @ dec_W^T[256,10000] + dec_b -> f32 d_out
    gemm_k256<1, true><<<dim3(128, 157), 256, 0, stream>>>(h2seq, nullptr, decW, decb, out, NVOC);

    // h1, h2 tails
    copy_hlast<<<32, 256, 0, stream>>>(h1seq, h2seq, out);
}

// Round 2
// 2303.917 us; speedup vs baseline: 2.5500x; 1.6859x over previous
//
#include <hip/hip_runtime.h>
#include <hip/hip_fp16.h>
#include <math.h>

// Problem constants: SEQ=256, B=32, NVOC=10000, NIN=NH=256, gates=4
#define SEQ   256
#define BATCH 32
#define NVOC  10000
#define NH    256
#define NG4   1024          // NH*4 gate columns
#define MTOT  8192          // SEQ*BATCH

typedef _Float16 h2_t __attribute__((ext_vector_type(2)));

__device__ __forceinline__ float fdot2f(h2_t a, h2_t b, float c) {
#if __has_builtin(__builtin_amdgcn_fdot2)
    return __builtin_amdgcn_fdot2(a, b, c, false);
#else
    return fmaf((float)a[0], (float)b[0], fmaf((float)a[1], (float)b[1], c));
#endif
}

// Generic K=256 f32 GEMM: C[M=8192][N] = A[8192][256] * B[256][N] + bias[N]
// AMODE 0: A rows gathered from embed_W via tokens; AMODE 1: A dense f32.
// BT false: B row-major [256][N]; BT true: B[k][n] = Bsrc[n*256+k] (dec_W is [NVOC][NH])
template<int AMODE, bool BT>
__global__ __launch_bounds__(256)
void gemm_k256(const float* __restrict__ Aptr, const int* __restrict__ tokens,
               const float* __restrict__ Bptr, const float* __restrict__ bias,
               float* __restrict__ Cptr, int N)
{
    __shared__ __align__(16) float As[32][68];   // [k][m], +4 pad: float4-aligned rows, no conflicts
    __shared__ __align__(16) float Bs[32][68];   // [k][n]
    __shared__ int rowTok[64];

    const int tid  = threadIdx.x;
    const int row0 = blockIdx.x * 64;
    const int col0 = blockIdx.y * 64;

    if (AMODE == 0) {
        if (tid < 64) rowTok[tid] = tokens[row0 + tid];
        __syncthreads();
    }

    float acc[4][4] = {};
    const int ty = tid >> 4, tx = tid & 15;    // 16x16 thread grid, 4x4 outputs each
    const int lr = tid >> 2, lq = tid & 3;     // loader: row 0..63, 8-elem segment 0..3

    for (int kb = 0; kb < 256; kb += 32) {
        // ---- global -> regs ----
        float av[8];
        {
            const int arow = (AMODE == 0) ? rowTok[lr] : (row0 + lr);
            const float* src = Aptr + (size_t)arow * 256 + kb + lq * 8;
            float4 v0 = *(const float4*)src;
            float4 v1 = *(const float4*)(src + 4);
            av[0]=v0.x; av[1]=v0.y; av[2]=v0.z; av[3]=v0.w;
            av[4]=v1.x; av[5]=v1.y; av[6]=v1.z; av[7]=v1.w;
        }
        float bv[8];
        if (!BT) {
            const int kk = tid >> 3, sg = tid & 7;   // 32 k-rows x 8 segments
            const float* src = Bptr + (size_t)(kb + kk) * N + col0 + sg * 8;
            float4 v0 = *(const float4*)src;
            float4 v1 = *(const float4*)(src + 4);
            bv[0]=v0.x; bv[1]=v0.y; bv[2]=v0.z; bv[3]=v0.w;
            bv[4]=v1.x; bv[5]=v1.y; bv[6]=v1.z; bv[7]=v1.w;
        } else {
            const int gcol = col0 + lr;
            if (gcol < N) {
                const float* src = Bptr + (size_t)gcol * 256 + kb + lq * 8;
                float4 v0 = *(const float4*)src;
                float4 v1 = *(const float4*)(src + 4);
                bv[0]=v0.x; bv[1]=v0.y; bv[2]=v0.z; bv[3]=v0.w;
                bv[4]=v1.x; bv[5]=v1.y; bv[6]=v1.z; bv[7]=v1.w;
            } else {
                #pragma unroll
                for (int j = 0; j < 8; j++) bv[j] = 0.f;
            }
        }

        __syncthreads();   // previous tile's LDS reads complete before overwrite
        #pragma unroll
        for (int j = 0; j < 8; j++) As[lq * 8 + j][lr] = av[j];
        if (!BT) {
            const int kk = tid >> 3, sg = tid & 7;
            #pragma unroll
            for (int j = 0; j < 8; j++) Bs[kk][sg * 8 + j] = bv[j];
        } else {
            #pragma unroll
            for (int j = 0; j < 8; j++) Bs[lq * 8 + j][lr] = bv[j];
        }
        __syncthreads();

        // ---- inner product ----
        #pragma unroll
        for (int kk = 0; kk < 32; kk++) {
            float4 af = *(const float4*)(&As[kk][ty * 4]);
            float4 bf = *(const float4*)(&Bs[kk][tx * 4]);
            float ar[4] = {af.x, af.y, af.z, af.w};
            float br[4] = {bf.x, bf.y, bf.z, bf.w};
            #pragma unroll
            for (int i = 0; i < 4; i++)
                #pragma unroll
                for (int j = 0; j < 4; j++)
                    acc[i][j] = fmaf(ar[i], br[j], acc[i][j]);
        }
    }

    // ---- epilogue: bias + store ----
    #pragma unroll
    for (int i = 0; i < 4; i++) {
        const int row = row0 + ty * 4 + i;     // M=8192 divisible by 64 -> always valid
        #pragma unroll
        for (int j = 0; j < 4; j++) {
            const int col = col0 + tx * 4 + j;
            if (col < N)
                Cptr[(size_t)row * N + col] = acc[i][j] + bias[col];
        }
    }
}

// Pack the register-resident slice: Wh f32 [256 h][1024 col] -> Wreg h2 [96][1024]
// Wreg[j][col] = (Wh[2j][col], Wh[2j+1][col]) for h = 0..191.
__global__ __launch_bounds__(256)
void pack_wreg(const float* __restrict__ Wh, h2_t* __restrict__ Wreg)
{
    const int idx = blockIdx.x * 256 + threadIdx.x;   // 0..98303 = j*1024 + col
    const int j   = idx >> 10;
    const int col = idx & 1023;
    h2_t v;
    v[0] = (_Float16)Wh[(size_t)(2 * j)     * NG4 + col];
    v[1] = (_Float16)Wh[(size_t)(2 * j + 1) * NG4 + col];
    Wreg[idx] = v;
}

// Pack the LDS-resident slice (h = 192..255): Wlds float4 [8][1024],
// Wlds[j4][col] = 8 halfs = Wh[192+j4*8 .. +7][col]
__global__ __launch_bounds__(256)
void pack_wlds(const float* __restrict__ Wh, float4* __restrict__ Wlds)
{
    const int idx = blockIdx.x * 256 + threadIdx.x;   // 0..8191 = j4*1024 + col
    const int j4  = idx >> 10;
    const int col = idx & 1023;
    const int h0  = 192 + j4 * 8;
    union { _Float16 h[8]; float4 v; } u;
    #pragma unroll
    for (int m = 0; m < 8; ++m)
        u.h[m] = (_Float16)Wh[(size_t)(h0 + m) * NG4 + col];
    Wlds[idx] = u.v;
}

// LSTM recurrence, one workgroup per batch element (grid=32, block=512).
// Weights stay ON-CU for the whole sequence: h[0:192) slice in 192 VGPRs/thread
// (2 columns x 96 half2), h[192:256) slice in 128 KB LDS. Per step the only
// global traffic is 2 gx floats/thread. Dot product = v_dot2_f32_f16 (f32 acc).
// gx: [SEQ*B][1024] f32 (bias included). hseq out: [SEQ*B][256] f32.
__global__ __launch_bounds__(512, 2)
void lstm_layer(const float* __restrict__ gx, const h2_t* __restrict__ Wreg,
                const float4* __restrict__ Wlds, float* __restrict__ hseq)
{
    const int b   = blockIdx.x;
    const int tid = threadIdx.x;                 // owns gate columns tid and tid+512
    __shared__ __align__(16) _Float16 hbuf[NH];  // 512 B, h as fp16
    __shared__ __align__(16) float    zbuf[NG4]; // 4 KB
    __shared__ __align__(16) _Float16 ldsw[8][NG4 * 8];  // 128 KB: [j4][col*8+m]

    // ---- one-time staging ----
    #pragma unroll
    for (int j4 = 0; j4 < 8; ++j4) {
        *reinterpret_cast<float4*>(&ldsw[j4][tid * 8])         = Wlds[j4 * NG4 + tid];
        *reinterpret_cast<float4*>(&ldsw[j4][(tid + 512) * 8]) = Wlds[j4 * NG4 + tid + 512];
    }
    h2_t wA[96], wB[96];
    #pragma unroll
    for (int j = 0; j < 96; ++j) {
        wA[j] = Wreg[j * NG4 + tid];
        wB[j] = Wreg[j * NG4 + tid + 512];
    }
    float c = 0.f;
    if (tid < NH) hbuf[tid] = (_Float16)0.f;
    __syncthreads();

    const h2_t* hb = reinterpret_cast<const h2_t*>(hbuf);

    for (int t = 0; t < SEQ; ++t) {
        const size_t base = ((size_t)t * BATCH + b) * NG4;
        const float g0 = gx[base + tid];          // issued early, consumed at the end
        const float g1 = gx[base + tid + 512];
        float a0 = 0.f, a1 = 0.f, a2 = 0.f, a3 = 0.f;
        float d0 = 0.f, d1 = 0.f, d2 = 0.f, d3 = 0.f;

        // h[0:192): register-resident weights, hbuf broadcast reads
        #pragma unroll
        for (int j = 0; j < 96; j += 4) {
            h2_t h0 = hb[j], h1 = hb[j + 1], h2 = hb[j + 2], h3 = hb[j + 3];
            a0 = fdot2f(wA[j],     h0, a0);
            a1 = fdot2f(wA[j + 1], h1, a1);
            a2 = fdot2f(wA[j + 2], h2, a2);
            a3 = fdot2f(wA[j + 3], h3, a3);
            d0 = fdot2f(wB[j],     h0, d0);
            d1 = fdot2f(wB[j + 1], h1, d1);
            d2 = fdot2f(wB[j + 2], h2, d2);
            d3 = fdot2f(wB[j + 3], h3, d3);
        }
        // h[192:256): LDS-resident weights, contiguous-per-lane b128 reads
        #pragma unroll
        for (int j4 = 0; j4 < 8; ++j4) {
            float4 wv0 = *reinterpret_cast<const float4*>(&ldsw[j4][tid * 8]);
            float4 wv1 = *reinterpret_cast<const float4*>(&ldsw[j4][(tid + 512) * 8]);
            const h2_t* p0 = reinterpret_cast<const h2_t*>(&wv0);
            const h2_t* p1 = reinterpret_cast<const h2_t*>(&wv1);
            h2_t h0 = hb[96 + j4 * 4 + 0], h1 = hb[96 + j4 * 4 + 1];
            h2_t h2 = hb[96 + j4 * 4 + 2], h3 = hb[96 + j4 * 4 + 3];
            a0 = fdot2f(p0[0], h0, a0);
            a1 = fdot2f(p0[1], h1, a1);
            a2 = fdot2f(p0[2], h2, a2);
            a3 = fdot2f(p0[3], h3, a3);
            d0 = fdot2f(p1[0], h0, d0);
            d1 = fdot2f(p1[1], h1, d1);
            d2 = fdot2f(p1[2], h2, d2);
            d3 = fdot2f(p1[3], h3, d3);
        }
        zbuf[tid]       = g0 + (a0 + a1) + (a2 + a3);
        zbuf[tid + 512] = g1 + (d0 + d1) + (d2 + d3);
        __syncthreads();                          // zbuf complete; hbuf reads complete

        if (tid < NH) {
            const float4 z4 = *reinterpret_cast<const float4*>(&zbuf[tid * 4]);
            float ig = 1.f / (1.f + expf(-z4.x));
            float fg = 1.f / (1.f + expf(-z4.y));
            float og = 1.f / (1.f + expf(-z4.z));
            float gg = tanhf(z4.w);
            c = fmaf(fg, c, ig * gg);
            float hn = og * tanhf(c);
            hbuf[tid] = (_Float16)hn;
            hseq[((size_t)t * BATCH + b) * NH + tid] = hn;
        }
        __syncthreads();                          // hbuf updated before next step
    }
}

// h1 = layer0 last hidden, h2 = layer1 last hidden -> appended to d_out (f32)
__global__ __launch_bounds__(256)
void copy_hlast(const float* __restrict__ h1seq, const float* __restrict__ h2seq,
                float* __restrict__ out)
{
    const int i = blockIdx.x * 256 + threadIdx.x;          // 0..8191 = b*256+k
    const size_t lastoff = (size_t)(SEQ - 1) * BATCH * NH; // 2088960
    out[(size_t)MTOT * NVOC + i]        = h1seq[lastoff + i];
    out[(size_t)MTOT * NVOC + 8192 + i] = h2seq[lastoff + i];
}

extern "C" void kernel_launch(void* const* d_in, const int* in_sizes, int n_in,
                              void* d_out, int out_size, void* d_ws, size_t ws_size,
                              hipStream_t stream)
{
    const int*   tokens = (const int*)d_in[0];
    const float* embed  = (const float*)d_in[1];
    const float* Wx0    = (const float*)d_in[2];
    const float* Wh0    = (const float*)d_in[3];
    const float* b0     = (const float*)d_in[4];
    const float* Wx1    = (const float*)d_in[5];
    const float* Wh1    = (const float*)d_in[6];
    const float* b1     = (const float*)d_in[7];
    const float* decW   = (const float*)d_in[8];
    const float* decb   = (const float*)d_in[9];

    float* out = (float*)d_out;

    // Scratch in the FRONT of d_out (328 MB): gx[8192][1024] f32 (33.5 MB), then the
    // packed fp16 weight images (0.5 MB per layer). Decoder GEMM overwrites all of it
    // at the end, after their last use. d_ws holds h1seq/h2seq only.
    float*  gx    = out;                                            // 33,554,432 B
    h2_t*   Wreg0 = reinterpret_cast<h2_t*>(out + (size_t)MTOT * NG4);
    float4* Wlds0 = reinterpret_cast<float4*>(Wreg0 + 96 * NG4);    // +384 KB
    h2_t*   Wreg1 = reinterpret_cast<h2_t*>(Wlds0 + 8 * NG4);       // +128 KB
    float4* Wlds1 = reinterpret_cast<float4*>(Wreg1 + 96 * NG4);
    float*  h1seq = (float*)d_ws;                 // 8,388,608 B
    float*  h2seq = h1seq + (size_t)MTOT * NH;    // 8,388,608 B (total 16.8 MB of ws)

    // pack fp16 weight images (runs once, independent of the gx GEMMs)
    pack_wreg<<<384, 256, 0, stream>>>(Wh0, Wreg0);
    pack_wlds<<<32, 256, 0, stream>>>(Wh0, Wlds0);
    pack_wreg<<<384, 256, 0, stream>>>(Wh1, Wreg1);
    pack_wlds<<<32, 256, 0, stream>>>(Wh1, Wlds1);

    // layer 0: gate inputs (embedding gather fused) then recurrence
    gemm_k256<0, false><<<dim3(128, 16), 256, 0, stream>>>(embed, tokens, Wx0, b0, gx, NG4);
    lstm_layer<<<32, 512, 0, stream>>>(gx, Wreg0, Wlds0, h1seq);

    // layer 1
    gemm_k256<1, false><<<dim3(128, 16), 256, 0, stream>>>(h1seq, nullptr, Wx1, b1, gx, NG4);
    lstm_layer<<<32, 512, 0, stream>>>(gx, Wreg1, Wlds1, h2seq);

    // decoder: [8192,256] @ dec_W^T[256,10000] + dec_b -> f32 d_out
    gemm_k256<1, true><<<dim3(128, 157), 256, 0, stream>>>(h2seq, nullptr, decW, decb, out, NVOC);

    // h1, h2 tails
    copy_hlast<<<32, 256, 0, stream>>>(h1seq, h2seq, out);
}

// Round 3
// 2011.278 us; speedup vs baseline: 2.9210x; 1.1455x over previous
//
#include <hip/hip_runtime.h>
#include <hip/hip_fp16.h>
#include <math.h>

// Problem constants: SEQ=256, B=32, NVOC=10000, NIN=NH=256, gates=4
#define SEQ   256
#define BATCH 32
#define NVOC  10000
#define NH    256
#define NG4   1024          // NH*4 gate columns
#define MTOT  8192          // SEQ*BATCH

typedef _Float16 h2_t __attribute__((ext_vector_type(2)));

__device__ __forceinline__ float fdot2f(h2_t a, h2_t b, float c) {
#if __has_builtin(__builtin_amdgcn_fdot2)
    return __builtin_amdgcn_fdot2(a, b, c, false);
#else
    return fmaf((float)a[0], (float)b[0], fmaf((float)a[1], (float)b[1], c));
#endif
}

#define LOG2E 1.4426950408889634f

// Branch-free fast sigmoid/tanh built on v_exp_f32/v_rcp_f32.
// Exact at +-inf; rel err ~1e-7 -- invisible vs the 1e-3 absmax budget.
__device__ __forceinline__ float fast_sigmoid(float x) {
    float e = __builtin_amdgcn_exp2f(-LOG2E * x);      // e^-x
    return __builtin_amdgcn_rcpf(1.f + e);
}
__device__ __forceinline__ float fast_tanh(float x) {
    float e = __builtin_amdgcn_exp2f((2.f * LOG2E) * x);  // e^{2x}
    return 1.f - 2.f * __builtin_amdgcn_rcpf(e + 1.f);
}

// Generic K=256 f32 GEMM: C[M=8192][N] = A[8192][256] * B[256][N] + bias[N]
// AMODE 0: A rows gathered from embed_W via tokens; AMODE 1: A dense f32.
// BT false: B row-major [256][N]; BT true: B[k][n] = Bsrc[n*256+k] (dec_W is [NVOC][NH])
template<int AMODE, bool BT>
__global__ __launch_bounds__(256)
void gemm_k256(const float* __restrict__ Aptr, const int* __restrict__ tokens,
               const float* __restrict__ Bptr, const float* __restrict__ bias,
               float* __restrict__ Cptr, int N)
{
    __shared__ __align__(16) float As[32][68];   // [k][m], +4 pad: float4-aligned rows, no conflicts
    __shared__ __align__(16) float Bs[32][68];   // [k][n]
    __shared__ int rowTok[64];

    const int tid  = threadIdx.x;
    const int row0 = blockIdx.x * 64;
    const int col0 = blockIdx.y * 64;

    if (AMODE == 0) {
        if (tid < 64) rowTok[tid] = tokens[row0 + tid];
        __syncthreads();
    }

    float acc[4][4] = {};
    const int ty = tid >> 4, tx = tid & 15;    // 16x16 thread grid, 4x4 outputs each
    const int lr = tid >> 2, lq = tid & 3;     // loader: row 0..63, 8-elem segment 0..3

    for (int kb = 0; kb < 256; kb += 32) {
        // ---- global -> regs ----
        float av[8];
        {
            const int arow = (AMODE == 0) ? rowTok[lr] : (row0 + lr);
            const float* src = Aptr + (size_t)arow * 256 + kb + lq * 8;
            float4 v0 = *(const float4*)src;
            float4 v1 = *(const float4*)(src + 4);
            av[0]=v0.x; av[1]=v0.y; av[2]=v0.z; av[3]=v0.w;
            av[4]=v1.x; av[5]=v1.y; av[6]=v1.z; av[7]=v1.w;
        }
        float bv[8];
        if (!BT) {
            const int kk = tid >> 3, sg = tid & 7;   // 32 k-rows x 8 segments
            const float* src = Bptr + (size_t)(kb + kk) * N + col0 + sg * 8;
            float4 v0 = *(const float4*)src;
            float4 v1 = *(const float4*)(src + 4);
            bv[0]=v0.x; bv[1]=v0.y; bv[2]=v0.z; bv[3]=v0.w;
            bv[4]=v1.x; bv[5]=v1.y; bv[6]=v1.z; bv[7]=v1.w;
        } else {
            const int gcol = col0 + lr;
            if (gcol < N) {
                const float* src = Bptr + (size_t)gcol * 256 + kb + lq * 8;
                float4 v0 = *(const float4*)src;
                float4 v1 = *(const float4*)(src + 4);
                bv[0]=v0.x; bv[1]=v0.y; bv[2]=v0.z; bv[3]=v0.w;
                bv[4]=v1.x; bv[5]=v1.y; bv[6]=v1.z; bv[7]=v1.w;
            } else {
                #pragma unroll
                for (int j = 0; j < 8; j++) bv[j] = 0.f;
            }
        }

        __syncthreads();   // previous tile's LDS reads complete before overwrite
        #pragma unroll
        for (int j = 0; j < 8; j++) As[lq * 8 + j][lr] = av[j];
        if (!BT) {
            const int kk = tid >> 3, sg = tid & 7;
            #pragma unroll
            for (int j = 0; j < 8; j++) Bs[kk][sg * 8 + j] = bv[j];
        } else {
            #pragma unroll
            for (int j = 0; j < 8; j++) Bs[lq * 8 + j][lr] = bv[j];
        }
        __syncthreads();

        // ---- inner product ----
        #pragma unroll
        for (int kk = 0; kk < 32; kk++) {
            float4 af = *(const float4*)(&As[kk][ty * 4]);
            float4 bf = *(const float4*)(&Bs[kk][tx * 4]);
            float ar[4] = {af.x, af.y, af.z, af.w};
            float br[4] = {bf.x, bf.y, bf.z, bf.w};
            #pragma unroll
            for (int i = 0; i < 4; i++)
                #pragma unroll
                for (int j = 0; j < 4; j++)
                    acc[i][j] = fmaf(ar[i], br[j], acc[i][j]);
        }
    }

    // ---- epilogue: bias + store ----
    #pragma unroll
    for (int i = 0; i < 4; i++) {
        const int row = row0 + ty * 4 + i;     // M=8192 divisible by 64 -> always valid
        #pragma unroll
        for (int j = 0; j < 4; j++) {
            const int col = col0 + tx * 4 + j;
            if (col < N)
                Cptr[(size_t)row * N + col] = acc[i][j] + bias[col];
        }
    }
}

// Pack the register-resident slice: Wh f32 [256 h][1024 col] -> Wreg h2 [96][1024]
// Wreg[j][col] = (Wh[2j][col], Wh[2j+1][col]) for h = 0..191.
__global__ __launch_bounds__(256)
void pack_wreg(const float* __restrict__ Wh, h2_t* __restrict__ Wreg)
{
    const int idx = blockIdx.x * 256 + threadIdx.x;   // 0..98303 = j*1024 + col
    const int j   = idx >> 10;
    const int col = idx & 1023;
    h2_t v;
    v[0] = (_Float16)Wh[(size_t)(2 * j)     * NG4 + col];
    v[1] = (_Float16)Wh[(size_t)(2 * j + 1) * NG4 + col];
    Wreg[idx] = v;
}

// Pack the LDS-resident slice (h = 192..255): Wlds float4 [8][1024],
// Wlds[j4][col] = 8 halfs = Wh[192+j4*8 .. +7][col]
__global__ __launch_bounds__(256)
void pack_wlds(const float* __restrict__ Wh, float4* __restrict__ Wlds)
{
    const int idx = blockIdx.x * 256 + threadIdx.x;   // 0..8191 = j4*1024 + col
    const int j4  = idx >> 10;
    const int col = idx & 1023;
    const int h0  = 192 + j4 * 8;
    union { _Float16 h[8]; float4 v; } u;
    #pragma unroll
    for (int m = 0; m < 8; ++m)
        u.h[m] = (_Float16)Wh[(size_t)(h0 + m) * NG4 + col];
    Wlds[idx] = u.v;
}

// LSTM recurrence, one workgroup per batch element (grid=32, block=512).
// Weights stay ON-CU for the whole sequence: h[0:192) slice in per-thread regs
// (2 columns x 96 half2; partially AGPR-backed), h[192:256) slice in 128 KB LDS.
// Serial-path fixes this round:
//  - gx double-buffered in regs: t+1 loads issued before t's dot phase, so the
//    vmcnt(0) drain at the barrier never exposes HBM latency.
//  - hseq store moved AFTER the second barrier: drains during next dot phase.
//  - branch-free exp2/rcp activation replaces libm expf/tanhf on the c->h chain.
__global__ __launch_bounds__(512, 2)
void lstm_layer(const float* __restrict__ gx, const h2_t* __restrict__ Wreg,
                const float4* __restrict__ Wlds, float* __restrict__ hseq)
{
    const int b   = blockIdx.x;
    const int tid = threadIdx.x;                 // owns gate columns tid and tid+512
    __shared__ __align__(16) _Float16 hbuf[NH];  // 512 B, h as fp16
    __shared__ __align__(16) float    zbuf[NG4]; // 4 KB
    __shared__ __align__(16) _Float16 ldsw[8][NG4 * 8];  // 128 KB: [j4][col*8+m]

    // ---- one-time staging ----
    #pragma unroll
    for (int j4 = 0; j4 < 8; ++j4) {
        *reinterpret_cast<float4*>(&ldsw[j4][tid * 8])         = Wlds[j4 * NG4 + tid];
        *reinterpret_cast<float4*>(&ldsw[j4][(tid + 512) * 8]) = Wlds[j4 * NG4 + tid + 512];
    }
    h2_t wA[96], wB[96];
    #pragma unroll
    for (int j = 0; j < 96; ++j) {
        wA[j] = Wreg[j * NG4 + tid];
        wB[j] = Wreg[j * NG4 + tid + 512];
    }
    float c = 0.f;
    if (tid < NH) hbuf[tid] = (_Float16)0.f;
    __syncthreads();

    const h2_t* hb = reinterpret_cast<const h2_t*>(hbuf);

    // prologue: t=0 gate inputs
    float g0 = gx[(size_t)b * NG4 + tid];
    float g1 = gx[(size_t)b * NG4 + tid + 512];

    for (int t = 0; t < SEQ; ++t) {
        // issue t+1's gx loads now; they complete under this step's dot phase
        const int tn = (t + 1 < SEQ) ? (t + 1) : t;
        const size_t nbase = ((size_t)tn * BATCH + b) * NG4;
        const float g0n = gx[nbase + tid];
        const float g1n = gx[nbase + tid + 512];

        float a0 = 0.f, a1 = 0.f, a2 = 0.f, a3 = 0.f;
        float d0 = 0.f, d1 = 0.f, d2 = 0.f, d3 = 0.f;

        // h[0:192): register-resident weights, hbuf broadcast reads
        #pragma unroll
        for (int j = 0; j < 96; j += 4) {
            h2_t h0 = hb[j], h1 = hb[j + 1], h2 = hb[j + 2], h3 = hb[j + 3];
            a0 = fdot2f(wA[j],     h0, a0);
            a1 = fdot2f(wA[j + 1], h1, a1);
            a2 = fdot2f(wA[j + 2], h2, a2);
            a3 = fdot2f(wA[j + 3], h3, a3);
            d0 = fdot2f(wB[j],     h0, d0);
            d1 = fdot2f(wB[j + 1], h1, d1);
            d2 = fdot2f(wB[j + 2], h2, d2);
            d3 = fdot2f(wB[j + 3], h3, d3);
        }
        // h[192:256): LDS-resident weights, contiguous-per-lane b128 reads
        #pragma unroll
        for (int j4 = 0; j4 < 8; ++j4) {
            float4 wv0 = *reinterpret_cast<const float4*>(&ldsw[j4][tid * 8]);
            float4 wv1 = *reinterpret_cast<const float4*>(&ldsw[j4][(tid + 512) * 8]);
            const h2_t* p0 = reinterpret_cast<const h2_t*>(&wv0);
            const h2_t* p1 = reinterpret_cast<const h2_t*>(&wv1);
            h2_t h0 = hb[96 + j4 * 4 + 0], h1 = hb[96 + j4 * 4 + 1];
            h2_t h2 = hb[96 + j4 * 4 + 2], h3 = hb[96 + j4 * 4 + 3];
            a0 = fdot2f(p0[0], h0, a0);
            a1 = fdot2f(p0[1], h1, a1);
            a2 = fdot2f(p0[2], h2, a2);
            a3 = fdot2f(p0[3], h3, a3);
            d0 = fdot2f(p1[0], h0, d0);
            d1 = fdot2f(p1[1], h1, d1);
            d2 = fdot2f(p1[2], h2, d2);
            d3 = fdot2f(p1[3], h3, d3);
        }
        zbuf[tid]       = g0 + (a0 + a1) + (a2 + a3);
        zbuf[tid + 512] = g1 + (d0 + d1) + (d2 + d3);
        __syncthreads();                          // zbuf complete; hbuf reads complete

        float hn = 0.f;
        if (tid < NH) {
            const float4 z4 = *reinterpret_cast<const float4*>(&zbuf[tid * 4]);
            float ig = fast_sigmoid(z4.x);
            float fg = fast_sigmoid(z4.y);
            float og = fast_sigmoid(z4.z);
            float gg = fast_tanh(z4.w);
            c = fmaf(fg, c, ig * gg);
            hn = og * fast_tanh(c);
            hbuf[tid] = (_Float16)hn;
        }
        __syncthreads();                          // hbuf updated before next step

        // store AFTER the barrier: the vmcnt drain lands in next step's dot phase
        if (tid < NH)
            hseq[((size_t)t * BATCH + b) * NH + tid] = hn;
        g0 = g0n;
        g1 = g1n;
    }
}

// h1 = layer0 last hidden, h2 = layer1 last hidden -> appended to d_out (f32)
__global__ __launch_bounds__(256)
void copy_hlast(const float* __restrict__ h1seq, const float* __restrict__ h2seq,
                float* __restrict__ out)
{
    const int i = blockIdx.x * 256 + threadIdx.x;          // 0..8191 = b*256+k
    const size_t lastoff = (size_t)(SEQ - 1) * BATCH * NH; // 2088960
    out[(size_t)MTOT * NVOC + i]        = h1seq[lastoff + i];
    out[(size_t)MTOT * NVOC + 8192 + i] = h2seq[lastoff + i];
}

extern "C" void kernel_launch(void* const* d_in, const int* in_sizes, int n_in,
                              void* d_out, int out_size, void* d_ws, size_t ws_size,
                              hipStream_t stream)
{
    const int*   tokens = (const int*)d_in[0];
    const float* embed  = (const float*)d_in[1];
    const float* Wx0    = (const float*)d_in[2];
    const float* Wh0    = (const float*)d_in[3];
    const float* b0     = (const float*)d_in[4];
    const float* Wx1    = (const float*)d_in[5];
    const float* Wh1    = (const float*)d_in[6];
    const float* b1     = (const float*)d_in[7];
    const float* decW   = (const float*)d_in[8];
    const float* decb   = (const float*)d_in[9];

    float* out = (float*)d_out;

    // Scratch in the FRONT of d_out (328 MB): gx[8192][1024] f32 (33.5 MB), then the
    // packed fp16 weight images (0.5 MB per layer). Decoder GEMM overwrites all of it
    // at the end, after their last use. d_ws holds h1seq/h2seq only.
    float*  gx    = out;                                            // 33,554,432 B
    h2_t*   Wreg0 = reinterpret_cast<h2_t*>(out + (size_t)MTOT * NG4);
    float4* Wlds0 = reinterpret_cast<float4*>(Wreg0 + 96 * NG4);    // +384 KB
    h2_t*   Wreg1 = reinterpret_cast<h2_t*>(Wlds0 + 8 * NG4);       // +128 KB
    float4* Wlds1 = reinterpret_cast<float4*>(Wreg1 + 96 * NG4);
    float*  h1seq = (float*)d_ws;                 // 8,388,608 B
    float*  h2seq = h1seq + (size_t)MTOT * NH;    // 8,388,608 B (total 16.8 MB of ws)

    // pack fp16 weight images (runs once, independent of the gx GEMMs)
    pack_wreg<<<384, 256, 0, stream>>>(Wh0, Wreg0);
    pack_wlds<<<32, 256, 0, stream>>>(Wh0, Wlds0);
    pack_wreg<<<384, 256, 0, stream>>>(Wh1, Wreg1);
    pack_wlds<<<32, 256, 0, stream>>>(Wh1, Wlds1);

    // layer 0: gate inputs (embedding gather fused) then recurrence
    gemm_k256<0, false><<<dim3(128, 16), 256, 0, stream>>>(embed, tokens, Wx0, b0, gx, NG4);
    lstm_layer<<<32, 512, 0, stream>>>(gx, Wreg0, Wlds0, h1seq);

    // layer 1
    gemm_k256<1, false><<<dim3(128, 16), 256, 0, stream>>>(h1seq, nullptr, Wx1, b1, gx, NG4);
    lstm_layer<<<32, 512, 0, stream>>>(gx, Wreg1, Wlds1, h2seq);

    // decoder: [8192,256] @ dec_W^T[256,10000] + dec_b -> f32 d_out
    gemm_k256<1, true><<<dim3(128, 157), 256, 0, stream>>>(h2seq, nullptr, decW, decb, out, NVOC);

    // h1, h2 tails
    copy_hlast<<<32, 256, 0, stream>>>(h1seq, h2seq, out);
}

// Round 4
// 1493.421 us; speedup vs baseline: 3.9339x; 1.3468x over previous
//
#include <hip/hip_runtime.h>
#include <hip/hip_fp16.h>
#include <math.h>

// Problem constants: SEQ=256, B=32, NVOC=10000, NIN=NH=256, gates=4
#define SEQ   256
#define BATCH 32
#define NVOC  10000
#define NH    256
#define NG4   1024          // NH*4 gate columns
#define MTOT  8192          // SEQ*BATCH

typedef _Float16 h2_t  __attribute__((ext_vector_type(2)));
typedef _Float16 f16x8 __attribute__((ext_vector_type(8)));
typedef float    f32x4 __attribute__((ext_vector_type(4)));

__device__ __forceinline__ float fdot2f(h2_t a, h2_t b, float c) {
#if __has_builtin(__builtin_amdgcn_fdot2)
    return __builtin_amdgcn_fdot2(a, b, c, false);
#else
    return fmaf((float)a[0], (float)b[0], fmaf((float)a[1], (float)b[1], c));
#endif
}

#define LOG2E 1.4426950408889634f

// Branch-free fast sigmoid/tanh built on v_exp_f32/v_rcp_f32.
__device__ __forceinline__ float fast_sigmoid(float x) {
    float e = __builtin_amdgcn_exp2f(-LOG2E * x);      // e^-x
    return __builtin_amdgcn_rcpf(1.f + e);
}
__device__ __forceinline__ float fast_tanh(float x) {
    float e = __builtin_amdgcn_exp2f((2.f * LOG2E) * x);  // e^{2x}
    return 1.f - 2.f * __builtin_amdgcn_rcpf(e + 1.f);
}

// ---------------------------------------------------------------------------
// MFMA fp16 GEMM: C[M=8192][N] = A[M][256] * B^T + bias, f32 out.
// A16: fp16 [M][256] (AMODE 1) or gathered rows embed16[tok[m]] (AMODE 0).
// B16: fp16 [N][256] (K contiguous per column -- "B^T" storage).
// 128x128 tile / block, 4 waves (2x2), each wave 64x64 = 4x4 16x16x32 frags.
// LDS is k-major [kseg][row][8]: staging writes and frag reads are both
// 16B/lane patterns that tile all 32 banks evenly (8 dwords/bank/wave).
// Fragment mapping (learn_hip-verified): A row=lane&15, k=(lane>>4)*8+j;
// C/D row=(lane>>4)*4+reg, col=lane&15.
// ---------------------------------------------------------------------------
template<int AMODE>
__global__ __launch_bounds__(256)
void mfma_gemm(const _Float16* __restrict__ A16, const int* __restrict__ tokens,
               const _Float16* __restrict__ B16, const float* __restrict__ bias,
               float* __restrict__ C, int N)
{
    __shared__ __align__(16) _Float16 As[4 * 128 * 8];   // 8 KB
    __shared__ __align__(16) _Float16 Bs[4 * 128 * 8];   // 8 KB
    __shared__ int rowTok[128];

    const int tid  = threadIdx.x;
    const int row0 = blockIdx.x * 128;
    const int col0 = blockIdx.y * 128;
    if (AMODE == 0) {
        if (tid < 128) rowTok[tid] = tokens[row0 + tid];
        __syncthreads();
    }

    const int lane = tid & 63;
    const int wave = tid >> 6;
    const int wr = (wave >> 1) * 64;     // wave row offset in tile
    const int wc = (wave & 1) * 64;      // wave col offset in tile
    const int fr = lane & 15;            // fragment row/col lane index
    const int ks = lane >> 4;            // k-segment 0..3 (k = ks*8 .. +7)

    const int lr = tid >> 2, ls = tid & 3;  // loader: row (chunk0), k-seg

    const int ar0 = (AMODE == 0) ? rowTok[lr]      : row0 + lr;
    const int ar1 = (AMODE == 0) ? rowTok[lr + 64] : row0 + lr + 64;
    const int bc0 = col0 + lr, bc1 = col0 + lr + 64;
    const bool b0ok = bc0 < N, b1ok = bc1 < N;

    f32x4 acc[4][4] = {};

    for (int kb = 0; kb < 256; kb += 32) {
        f16x8 a0 = *(const f16x8*)(A16 + (size_t)ar0 * 256 + kb + ls * 8);
        f16x8 a1 = *(const f16x8*)(A16 + (size_t)ar1 * 256 + kb + ls * 8);
        f16x8 b0 = {}, b1 = {};
        if (b0ok) b0 = *(const f16x8*)(B16 + (size_t)bc0 * 256 + kb + ls * 8);
        if (b1ok) b1 = *(const f16x8*)(B16 + (size_t)bc1 * 256 + kb + ls * 8);

        __syncthreads();          // prior iteration's fragment reads complete
        *(f16x8*)(As + (ls * 128 + lr) * 8)        = a0;
        *(f16x8*)(As + (ls * 128 + lr + 64) * 8)   = a1;
        *(f16x8*)(Bs + (ls * 128 + lr) * 8)        = b0;
        *(f16x8*)(Bs + (ls * 128 + lr + 64) * 8)   = b1;
        __syncthreads();

        f16x8 af[4], bf[4];
        #pragma unroll
        for (int i = 0; i < 4; ++i)
            af[i] = *(const f16x8*)(As + (ks * 128 + wr + i * 16 + fr) * 8);
        #pragma unroll
        for (int j = 0; j < 4; ++j)
            bf[j] = *(const f16x8*)(Bs + (ks * 128 + wc + j * 16 + fr) * 8);
        #pragma unroll
        for (int i = 0; i < 4; ++i)
            #pragma unroll
            for (int j = 0; j < 4; ++j)
                acc[i][j] = __builtin_amdgcn_mfma_f32_16x16x32_f16(af[i], bf[j], acc[i][j], 0, 0, 0);
    }

    // epilogue: bias + f32 store (col-masked for the decoder tail tile)
    #pragma unroll
    for (int j = 0; j < 4; ++j) {
        const int col = col0 + wc + j * 16 + fr;
        if (col >= N) continue;
        const float bs = bias[col];
        #pragma unroll
        for (int i = 0; i < 4; ++i) {
            const int rbase = row0 + wr + i * 16 + ks * 4;
            #pragma unroll
            for (int r = 0; r < 4; ++r)
                C[(size_t)(rbase + r) * N + col] = acc[i][j][r] + bs;
        }
    }
}

// ---------------------------------------------------------------------------
// Packing kernels
// ---------------------------------------------------------------------------

// f32 -> fp16 elementwise, 8 per thread (embed_W, dec_W: [rows][256], layout kept)
__global__ __launch_bounds__(256)
void pack_f16(const float* __restrict__ src, _Float16* __restrict__ dst, int n8)
{
    const int i = blockIdx.x * 256 + threadIdx.x;
    if (i >= n8) return;
    const float4 v0 = *(const float4*)(src + (size_t)i * 8);
    const float4 v1 = *(const float4*)(src + (size_t)i * 8 + 4);
    f16x8 o = { (_Float16)v0.x, (_Float16)v0.y, (_Float16)v0.z, (_Float16)v0.w,
                (_Float16)v1.x, (_Float16)v1.y, (_Float16)v1.z, (_Float16)v1.w };
    *(f16x8*)(dst + (size_t)i * 8) = o;
}

// Wx [256][1024] f32 -> WxT fp16 [1024 cols][256 k] (decoder-style B^T layout)
__global__ __launch_bounds__(256)
void pack_wxT(const float* __restrict__ Wx, _Float16* __restrict__ WxT)
{
    const int idx = blockIdx.x * 256 + threadIdx.x;   // 0..262143 = n*256 + k
    const int n = idx >> 8, k = idx & 255;
    WxT[idx] = (_Float16)Wx[(size_t)k * NG4 + n];
}

// Pack the register-resident slice: Wh f32 [256 h][1024 col] -> Wreg h2 [96][1024]
__global__ __launch_bounds__(256)
void pack_wreg(const float* __restrict__ Wh, h2_t* __restrict__ Wreg)
{
    const int idx = blockIdx.x * 256 + threadIdx.x;   // 0..98303 = j*1024 + col
    const int j   = idx >> 10;
    const int col = idx & 1023;
    h2_t v;
    v[0] = (_Float16)Wh[(size_t)(2 * j)     * NG4 + col];
    v[1] = (_Float16)Wh[(size_t)(2 * j + 1) * NG4 + col];
    Wreg[idx] = v;
}

// Pack the LDS-resident slice (h = 192..255): Wlds float4 [8][1024]
__global__ __launch_bounds__(256)
void pack_wlds(const float* __restrict__ Wh, float4* __restrict__ Wlds)
{
    const int idx = blockIdx.x * 256 + threadIdx.x;   // 0..8191 = j4*1024 + col
    const int j4  = idx >> 10;
    const int col = idx & 1023;
    const int h0  = 192 + j4 * 8;
    union { _Float16 h[8]; float4 v; } u;
    #pragma unroll
    for (int m = 0; m < 8; ++m)
        u.h[m] = (_Float16)Wh[(size_t)(h0 + m) * NG4 + col];
    Wlds[idx] = u.v;
}

// ---------------------------------------------------------------------------
// LSTM recurrence, one workgroup per batch element (grid=32, block=512).
// Weights stay ON-CU for the whole sequence. hseq output is fp16 (feeds the
// next MFMA GEMM's A operand directly; halves the store traffic).
// ---------------------------------------------------------------------------
__global__ __launch_bounds__(512, 2)
void lstm_layer(const float* __restrict__ gx, const h2_t* __restrict__ Wreg,
                const float4* __restrict__ Wlds, _Float16* __restrict__ hseq16)
{
    const int b   = blockIdx.x;
    const int tid = threadIdx.x;                 // owns gate columns tid and tid+512
    __shared__ __align__(16) _Float16 hbuf[NH];  // 512 B, h as fp16
    __shared__ __align__(16) float    zbuf[NG4]; // 4 KB
    __shared__ __align__(16) _Float16 ldsw[8][NG4 * 8];  // 128 KB: [j4][col*8+m]

    // ---- one-time staging ----
    #pragma unroll
    for (int j4 = 0; j4 < 8; ++j4) {
        *reinterpret_cast<float4*>(&ldsw[j4][tid * 8])         = Wlds[j4 * NG4 + tid];
        *reinterpret_cast<float4*>(&ldsw[j4][(tid + 512) * 8]) = Wlds[j4 * NG4 + tid + 512];
    }
    h2_t wA[96], wB[96];
    #pragma unroll
    for (int j = 0; j < 96; ++j) {
        wA[j] = Wreg[j * NG4 + tid];
        wB[j] = Wreg[j * NG4 + tid + 512];
    }
    float c = 0.f;
    if (tid < NH) hbuf[tid] = (_Float16)0.f;
    __syncthreads();

    const h2_t* hb = reinterpret_cast<const h2_t*>(hbuf);

    // prologue: t=0 gate inputs
    float g0 = gx[(size_t)b * NG4 + tid];
    float g1 = gx[(size_t)b * NG4 + tid + 512];

    for (int t = 0; t < SEQ; ++t) {
        // issue t+1's gx loads now; they complete under this step's dot phase
        const int tn = (t + 1 < SEQ) ? (t + 1) : t;
        const size_t nbase = ((size_t)tn * BATCH + b) * NG4;
        const float g0n = gx[nbase + tid];
        const float g1n = gx[nbase + tid + 512];

        float a0 = 0.f, a1 = 0.f, a2 = 0.f, a3 = 0.f;
        float d0 = 0.f, d1 = 0.f, d2 = 0.f, d3 = 0.f;

        // h[0:192): register-resident weights, hbuf broadcast reads
        #pragma unroll
        for (int j = 0; j < 96; j += 4) {
            h2_t h0 = hb[j], h1 = hb[j + 1], h2 = hb[j + 2], h3 = hb[j + 3];
            a0 = fdot2f(wA[j],     h0, a0);
            a1 = fdot2f(wA[j + 1], h1, a1);
            a2 = fdot2f(wA[j + 2], h2, a2);
            a3 = fdot2f(wA[j + 3], h3, a3);
            d0 = fdot2f(wB[j],     h0, d0);
            d1 = fdot2f(wB[j + 1], h1, d1);
            d2 = fdot2f(wB[j + 2], h2, d2);
            d3 = fdot2f(wB[j + 3], h3, d3);
        }
        // h[192:256): LDS-resident weights, contiguous-per-lane b128 reads
        #pragma unroll
        for (int j4 = 0; j4 < 8; ++j4) {
            float4 wv0 = *reinterpret_cast<const float4*>(&ldsw[j4][tid * 8]);
            float4 wv1 = *reinterpret_cast<const float4*>(&ldsw[j4][(tid + 512) * 8]);
            const h2_t* p0 = reinterpret_cast<const h2_t*>(&wv0);
            const h2_t* p1 = reinterpret_cast<const h2_t*>(&wv1);
            h2_t h0 = hb[96 + j4 * 4 + 0], h1 = hb[96 + j4 * 4 + 1];
            h2_t h2 = hb[96 + j4 * 4 + 2], h3 = hb[96 + j4 * 4 + 3];
            a0 = fdot2f(p0[0], h0, a0);
            a1 = fdot2f(p0[1], h1, a1);
            a2 = fdot2f(p0[2], h2, a2);
            a3 = fdot2f(p0[3], h3, a3);
            d0 = fdot2f(p1[0], h0, d0);
            d1 = fdot2f(p1[1], h1, d1);
            d2 = fdot2f(p1[2], h2, d2);
            d3 = fdot2f(p1[3], h3, d3);
        }
        zbuf[tid]       = g0 + (a0 + a1) + (a2 + a3);
        zbuf[tid + 512] = g1 + (d0 + d1) + (d2 + d3);
        __syncthreads();                          // zbuf complete; hbuf reads complete

        float hn = 0.f;
        if (tid < NH) {
            const float4 z4 = *reinterpret_cast<const float4*>(&zbuf[tid * 4]);
            float ig = fast_sigmoid(z4.x);
            float fg = fast_sigmoid(z4.y);
            float og = fast_sigmoid(z4.z);
            float gg = fast_tanh(z4.w);
            c = fmaf(fg, c, ig * gg);
            hn = og * fast_tanh(c);
            hbuf[tid] = (_Float16)hn;
        }
        __syncthreads();                          // hbuf updated before next step

        // store AFTER the barrier: the vmcnt drain lands in next step's dot phase
        if (tid < NH)
            hseq16[((size_t)t * BATCH + b) * NH + tid] = (_Float16)hn;
        g0 = g0n;
        g1 = g1n;
    }
}

// h1 = layer0 last hidden, h2 = layer1 last hidden -> appended to d_out (f32)
__global__ __launch_bounds__(256)
void copy_hlast(const _Float16* __restrict__ h1seq16, const _Float16* __restrict__ h2seq16,
                float* __restrict__ out)
{
    const int i = blockIdx.x * 256 + threadIdx.x;          // 0..8191 = b*256+k
    const size_t lastoff = (size_t)(SEQ - 1) * BATCH * NH; // 2088960
    out[(size_t)MTOT * NVOC + i]        = (float)h1seq16[lastoff + i];
    out[(size_t)MTOT * NVOC + 8192 + i] = (float)h2seq16[lastoff + i];
}

extern "C" void kernel_launch(void* const* d_in, const int* in_sizes, int n_in,
                              void* d_out, int out_size, void* d_ws, size_t ws_size,
                              hipStream_t stream)
{
    const int*   tokens = (const int*)d_in[0];
    const float* embed  = (const float*)d_in[1];
    const float* Wx0    = (const float*)d_in[2];
    const float* Wh0    = (const float*)d_in[3];
    const float* b0     = (const float*)d_in[4];
    const float* Wx1    = (const float*)d_in[5];
    const float* Wh1    = (const float*)d_in[6];
    const float* b1     = (const float*)d_in[7];
    const float* decW   = (const float*)d_in[8];
    const float* decb   = (const float*)d_in[9];

    float* out = (float*)d_out;

    // Scratch in the FRONT of d_out (328 MB) -- everything here is DEAD before the
    // decoder GEMM overwrites it: gx (33.5 MB), Wreg/Wlds images (1 MB),
    // embed16 (5.12 MB), Wx0T/Wx1T (0.5 MB each).
    float*    gx      = out;                                                   // 33,554,432 B
    h2_t*     Wreg0   = reinterpret_cast<h2_t*>(out + (size_t)MTOT * NG4);
    float4*   Wlds0   = reinterpret_cast<float4*>(Wreg0 + 96 * NG4);           // +384 KB
    h2_t*     Wreg1   = reinterpret_cast<h2_t*>(Wlds0 + 8 * NG4);              // +128 KB
    float4*   Wlds1   = reinterpret_cast<float4*>(Wreg1 + 96 * NG4);
    _Float16* embed16 = reinterpret_cast<_Float16*>(Wlds1 + 8 * NG4);          // 5,120,000 B
    _Float16* Wx0T    = embed16 + (size_t)NVOC * NH;                           // 524,288 B
    _Float16* Wx1T    = Wx0T + (size_t)NG4 * NH;                               // 524,288 B

    // d_ws: read DURING the decoder GEMM -> must not alias d_out.
    _Float16* h1seq16 = (_Float16*)d_ws;                      // 4,194,304 B
    _Float16* h2seq16 = h1seq16 + (size_t)MTOT * NH;          // 4,194,304 B
    _Float16* dec16   = h2seq16 + (size_t)MTOT * NH;          // 5,120,000 B (13.5 MB total)

    // ---- packs (all independent; run up-front) ----
    pack_wreg<<<384, 256, 0, stream>>>(Wh0, Wreg0);
    pack_wlds<<<32, 256, 0, stream>>>(Wh0, Wlds0);
    pack_wreg<<<384, 256, 0, stream>>>(Wh1, Wreg1);
    pack_wlds<<<32, 256, 0, stream>>>(Wh1, Wlds1);
    pack_f16<<<1250, 256, 0, stream>>>(embed, embed16, NVOC * NH / 8);
    pack_f16<<<1250, 256, 0, stream>>>(decW, dec16, NVOC * NH / 8);
    pack_wxT<<<1024, 256, 0, stream>>>(Wx0, Wx0T);
    pack_wxT<<<1024, 256, 0, stream>>>(Wx1, Wx1T);

    // layer 0: gate inputs (embedding gather fused into MFMA GEMM) then recurrence
    mfma_gemm<0><<<dim3(64, 8), 256, 0, stream>>>(embed16, tokens, Wx0T, b0, gx, NG4);
    lstm_layer<<<32, 512, 0, stream>>>(gx, Wreg0, Wlds0, h1seq16);

    // layer 1
    mfma_gemm<1><<<dim3(64, 8), 256, 0, stream>>>(h1seq16, nullptr, Wx1T, b1, gx, NG4);
    lstm_layer<<<32, 512, 0, stream>>>(gx, Wreg1, Wlds1, h2seq16);

    // decoder: [8192,256] @ dec16^T[256,10000] + dec_b -> f32 d_out
    mfma_gemm<1><<<dim3(64, 79), 256, 0, stream>>>(h2seq16, nullptr, dec16, decb, out, NVOC);

    // h1, h2 tails
    copy_hlast<<<32, 256, 0, stream>>>(h1seq16, h2seq16, out);
}